// Round 1
// baseline (2022.295 us; speedup 1.0000x reference)
//
#include <hip/hip_runtime.h>
#include <math.h>

#define TSEQ   4096
#define DMODEL 768
#define NHEADS 12
#define DKH    64
#define DFF    3072

// ---------------------------------------------------------------------------
// Generic fp32 GEMM: C[M,N] = act(A[M,K] @ W[K,N] + bias (+ R))
// BM=BN=128, BK=16, 256 threads, 8x8 per thread.
// ---------------------------------------------------------------------------
template<int RELU, int RESID>
__global__ __launch_bounds__(256)
void gemm_generic(const float* __restrict__ A, const float* __restrict__ W,
                  const float* __restrict__ bias, const float* __restrict__ R,
                  float* __restrict__ C, int M, int N, int K)
{
    __shared__ float as[16][132];   // as[kk][row]  (A transposed in LDS)
    __shared__ float bs[16][132];   // bs[kk][col]
    const int tid = threadIdx.x;
    const int ty = tid >> 4, tx = tid & 15;
    const int m0 = blockIdx.y << 7;
    const int n0 = blockIdx.x << 7;

    float acc[8][8];
#pragma unroll
    for (int i = 0; i < 8; ++i)
#pragma unroll
        for (int j = 0; j < 8; ++j) acc[i][j] = 0.f;

    for (int k0 = 0; k0 < K; k0 += 16) {
        float4 av[2], bv[2];
#pragma unroll
        for (int s = 0; s < 2; ++s) {
            int li = tid + s * 256;
            int arow = li >> 2, akq = li & 3;
            av[s] = *(const float4*)(A + (size_t)(m0 + arow) * K + k0 + akq * 4);
            int bk = li >> 5, bn = li & 31;
            bv[s] = *(const float4*)(W + (size_t)(k0 + bk) * N + n0 + bn * 4);
        }
        __syncthreads();   // previous compute done reading LDS
#pragma unroll
        for (int s = 0; s < 2; ++s) {
            int li = tid + s * 256;
            int arow = li >> 2, akq = li & 3;
            as[akq * 4 + 0][arow] = av[s].x;
            as[akq * 4 + 1][arow] = av[s].y;
            as[akq * 4 + 2][arow] = av[s].z;
            as[akq * 4 + 3][arow] = av[s].w;
            int bk = li >> 5, bn = li & 31;
            *(float4*)&bs[bk][bn * 4] = bv[s];
        }
        __syncthreads();
#pragma unroll
        for (int kk = 0; kk < 16; ++kk) {
            float ar[8], br[8];
            float4 t;
            t = *(const float4*)&as[kk][ty * 4];      ar[0]=t.x; ar[1]=t.y; ar[2]=t.z; ar[3]=t.w;
            t = *(const float4*)&as[kk][64 + ty * 4]; ar[4]=t.x; ar[5]=t.y; ar[6]=t.z; ar[7]=t.w;
            t = *(const float4*)&bs[kk][tx * 4];      br[0]=t.x; br[1]=t.y; br[2]=t.z; br[3]=t.w;
            t = *(const float4*)&bs[kk][64 + tx * 4]; br[4]=t.x; br[5]=t.y; br[6]=t.z; br[7]=t.w;
#pragma unroll
            for (int i = 0; i < 8; ++i)
#pragma unroll
                for (int j = 0; j < 8; ++j)
                    acc[i][j] = fmaf(ar[i], br[j], acc[i][j]);
        }
    }

#pragma unroll
    for (int i = 0; i < 8; ++i) {
        int row = m0 + ((i & 4) << 4) + ty * 4 + (i & 3);
#pragma unroll
        for (int jh = 0; jh < 2; ++jh) {
            int col = n0 + (jh << 6) + tx * 4;
            float4 r;
            r.x = acc[i][jh * 4 + 0];
            r.y = acc[i][jh * 4 + 1];
            r.z = acc[i][jh * 4 + 2];
            r.w = acc[i][jh * 4 + 3];
            float4 bb = *(const float4*)(bias + col);
            r.x += bb.x; r.y += bb.y; r.z += bb.z; r.w += bb.w;
            if (RESID) {
                float4 rr = *(const float4*)(R + (size_t)row * N + col);
                r.x += rr.x; r.y += rr.y; r.z += rr.z; r.w += rr.w;
            }
            if (RELU) {
                r.x = fmaxf(r.x, 0.f); r.y = fmaxf(r.y, 0.f);
                r.z = fmaxf(r.z, 0.f); r.w = fmaxf(r.w, 0.f);
            }
            *(float4*)(C + (size_t)row * N + col) = r;
        }
    }
}

// ---------------------------------------------------------------------------
// Fused QKV GEMM: treats N as 3*768; writes Q,K,V head-major [12][4096][64].
// Q is pre-scaled by 1/sqrt(dk) = 0.125.
// ---------------------------------------------------------------------------
__global__ __launch_bounds__(256)
void gemm_qkv(const float* __restrict__ A,
              const float* __restrict__ Wq, const float* __restrict__ bq,
              const float* __restrict__ Wk, const float* __restrict__ bk,
              const float* __restrict__ Wv, const float* __restrict__ bv,
              float* __restrict__ ws)
{
    __shared__ float as[16][132];
    __shared__ float bs[16][132];
    const int tid = threadIdx.x;
    const int ty = tid >> 4, tx = tid & 15;
    const int m0 = blockIdx.y << 7;
    const int w  = blockIdx.x / 6;            // 0=Q 1=K 2=V
    const int n0 = (blockIdx.x % 6) << 7;     // col within the 768-wide matrix
    const int K = DMODEL, N = DMODEL;

    const float* W = (w == 0) ? Wq : (w == 1) ? Wk : Wv;
    const float* bb = (w == 0) ? bq : (w == 1) ? bk : bv;
    float* outb = ws + (size_t)w * (TSEQ * DMODEL);
    const float scale = (w == 0) ? 0.125f : 1.0f;

    float acc[8][8];
#pragma unroll
    for (int i = 0; i < 8; ++i)
#pragma unroll
        for (int j = 0; j < 8; ++j) acc[i][j] = 0.f;

    for (int k0 = 0; k0 < K; k0 += 16) {
        float4 av[2], bv4[2];
#pragma unroll
        for (int s = 0; s < 2; ++s) {
            int li = tid + s * 256;
            int arow = li >> 2, akq = li & 3;
            av[s] = *(const float4*)(A + (size_t)(m0 + arow) * K + k0 + akq * 4);
            int bk2 = li >> 5, bn = li & 31;
            bv4[s] = *(const float4*)(W + (size_t)(k0 + bk2) * N + n0 + bn * 4);
        }
        __syncthreads();
#pragma unroll
        for (int s = 0; s < 2; ++s) {
            int li = tid + s * 256;
            int arow = li >> 2, akq = li & 3;
            as[akq * 4 + 0][arow] = av[s].x;
            as[akq * 4 + 1][arow] = av[s].y;
            as[akq * 4 + 2][arow] = av[s].z;
            as[akq * 4 + 3][arow] = av[s].w;
            int bk2 = li >> 5, bn = li & 31;
            *(float4*)&bs[bk2][bn * 4] = bv4[s];
        }
        __syncthreads();
#pragma unroll
        for (int kk = 0; kk < 16; ++kk) {
            float ar[8], br[8];
            float4 t;
            t = *(const float4*)&as[kk][ty * 4];      ar[0]=t.x; ar[1]=t.y; ar[2]=t.z; ar[3]=t.w;
            t = *(const float4*)&as[kk][64 + ty * 4]; ar[4]=t.x; ar[5]=t.y; ar[6]=t.z; ar[7]=t.w;
            t = *(const float4*)&bs[kk][tx * 4];      br[0]=t.x; br[1]=t.y; br[2]=t.z; br[3]=t.w;
            t = *(const float4*)&bs[kk][64 + tx * 4]; br[4]=t.x; br[5]=t.y; br[6]=t.z; br[7]=t.w;
#pragma unroll
            for (int i = 0; i < 8; ++i)
#pragma unroll
                for (int j = 0; j < 8; ++j)
                    acc[i][j] = fmaf(ar[i], br[j], acc[i][j]);
        }
    }

#pragma unroll
    for (int i = 0; i < 8; ++i) {
        int row = m0 + ((i & 4) << 4) + ty * 4 + (i & 3);
#pragma unroll
        for (int jh = 0; jh < 2; ++jh) {
            int nn = n0 + (jh << 6) + tx * 4;      // 0..767
            int h = nn >> 6;
            int d = nn & 63;
            float4 r;
            r.x = acc[i][jh * 4 + 0];
            r.y = acc[i][jh * 4 + 1];
            r.z = acc[i][jh * 4 + 2];
            r.w = acc[i][jh * 4 + 3];
            float4 bbv = *(const float4*)(bb + nn);
            r.x = (r.x + bbv.x) * scale;
            r.y = (r.y + bbv.y) * scale;
            r.z = (r.z + bbv.z) * scale;
            r.w = (r.w + bbv.w) * scale;
            *(float4*)(outb + (size_t)h * (TSEQ * DKH) + (size_t)row * DKH + d) = r;
        }
    }
}

// ---------------------------------------------------------------------------
// Flash attention, fp32, causal. One block = 64 q-rows of one head.
// grid (64, 12), 256 threads. Q pre-scaled by 0.125 at QKV time.
// ---------------------------------------------------------------------------
__global__ __launch_bounds__(256)
void attn_kernel(const float* __restrict__ qkv, float* __restrict__ ctx)
{
    __shared__ float QT[64][68];   // QT[d][r]
    __shared__ float KVs[64][68];  // K as [d][c]; later V as [c][d]
    __shared__ float PT[64][68];   // PT[c][r]

    const int tid = threadIdx.x;
    const int ty = tid >> 4, tx = tid & 15;
    const int qb = 63 - blockIdx.x;          // heavy blocks first
    const int h = blockIdx.y;
    const int q0 = qb * 64;

    const float* Qh = qkv + (size_t)h * (TSEQ * DKH);
    const float* Kh = qkv + (size_t)(TSEQ * DMODEL) + (size_t)h * (TSEQ * DKH);
    const float* Vh = qkv + (size_t)(2 * TSEQ * DMODEL) + (size_t)h * (TSEQ * DKH);

    // load Q transposed
#pragma unroll
    for (int s = 0; s < 4; ++s) {
        int li = tid + s * 256;
        int row = li >> 4, d4 = li & 15;
        float4 v = *(const float4*)(Qh + (size_t)(q0 + row) * DKH + d4 * 4);
        QT[d4 * 4 + 0][row] = v.x;
        QT[d4 * 4 + 1][row] = v.y;
        QT[d4 * 4 + 2][row] = v.z;
        QT[d4 * 4 + 3][row] = v.w;
    }

    float o[4][4];
    float m_[4], l_[4];
#pragma unroll
    for (int i = 0; i < 4; ++i) {
        m_[i] = -3.402823e38f;
        l_[i] = 0.f;
#pragma unroll
        for (int j = 0; j < 4; ++j) o[i][j] = 0.f;
    }
    __syncthreads();

    for (int kb = 0; kb <= qb; ++kb) {
        __syncthreads();   // prev PV done reading KVs
        // K tile, transposed: KVs[d][c]
#pragma unroll
        for (int s = 0; s < 4; ++s) {
            int li = tid + s * 256;
            int row = li >> 4, d4 = li & 15;
            float4 v = *(const float4*)(Kh + (size_t)(kb * 64 + row) * DKH + d4 * 4);
            KVs[d4 * 4 + 0][row] = v.x;
            KVs[d4 * 4 + 1][row] = v.y;
            KVs[d4 * 4 + 2][row] = v.z;
            KVs[d4 * 4 + 3][row] = v.w;
        }
        __syncthreads();

        float s4[4][4];
#pragma unroll
        for (int i = 0; i < 4; ++i)
#pragma unroll
            for (int j = 0; j < 4; ++j) s4[i][j] = 0.f;

#pragma unroll 8
        for (int d = 0; d < 64; ++d) {
            float qa[4], ka[4];
            float4 t;
            t = *(const float4*)&QT[d][ty * 4];  qa[0]=t.x; qa[1]=t.y; qa[2]=t.z; qa[3]=t.w;
            t = *(const float4*)&KVs[d][tx * 4]; ka[0]=t.x; ka[1]=t.y; ka[2]=t.z; ka[3]=t.w;
#pragma unroll
            for (int i = 0; i < 4; ++i)
#pragma unroll
                for (int j = 0; j < 4; ++j)
                    s4[i][j] = fmaf(qa[i], ka[j], s4[i][j]);
        }

        if (kb == qb) {
#pragma unroll
            for (int i = 0; i < 4; ++i)
#pragma unroll
                for (int j = 0; j < 4; ++j)
                    if (tx * 4 + j > ty * 4 + i) s4[i][j] = -3.0e38f;
        }

        // online softmax
#pragma unroll
        for (int i = 0; i < 4; ++i) {
            float rm = fmaxf(fmaxf(s4[i][0], s4[i][1]), fmaxf(s4[i][2], s4[i][3]));
#pragma unroll
            for (int off = 1; off < 16; off <<= 1)
                rm = fmaxf(rm, __shfl_xor(rm, off, 16));
            float mn = fmaxf(m_[i], rm);
            float scl = __expf(m_[i] - mn);
            m_[i] = mn;
            float rs = 0.f;
#pragma unroll
            for (int j = 0; j < 4; ++j) {
                s4[i][j] = __expf(s4[i][j] - mn);
                rs += s4[i][j];
            }
#pragma unroll
            for (int off = 1; off < 16; off <<= 1)
                rs += __shfl_xor(rs, off, 16);
            l_[i] = l_[i] * scl + rs;
#pragma unroll
            for (int j = 0; j < 4; ++j) o[i][j] *= scl;
        }

        // store P transposed: PT[c][r]
#pragma unroll
        for (int j = 0; j < 4; ++j) {
            float4 c;
            c.x = s4[0][j]; c.y = s4[1][j]; c.z = s4[2][j]; c.w = s4[3][j];
            *(float4*)&PT[tx * 4 + j][ty * 4] = c;
        }
        __syncthreads();   // KVs reads done (S) + PT visible

        // V tile, natural: KVs[c][d]
#pragma unroll
        for (int s = 0; s < 4; ++s) {
            int li = tid + s * 256;
            int row = li >> 4, d4 = li & 15;
            float4 v = *(const float4*)(Vh + (size_t)(kb * 64 + row) * DKH + d4 * 4);
            *(float4*)&KVs[row][d4 * 4] = v;
        }
        __syncthreads();

        // O += P @ V
#pragma unroll 8
        for (int c = 0; c < 64; ++c) {
            float pa[4], vb[4];
            float4 t;
            t = *(const float4*)&PT[c][ty * 4];  pa[0]=t.x; pa[1]=t.y; pa[2]=t.z; pa[3]=t.w;
            t = *(const float4*)&KVs[c][tx * 4]; vb[0]=t.x; vb[1]=t.y; vb[2]=t.z; vb[3]=t.w;
#pragma unroll
            for (int i = 0; i < 4; ++i)
#pragma unroll
                for (int j = 0; j < 4; ++j)
                    o[i][j] = fmaf(pa[i], vb[j], o[i][j]);
        }
    }

    // write context token-major [T, 768]
#pragma unroll
    for (int i = 0; i < 4; ++i) {
        float inv = 1.0f / l_[i];
        float4 r;
        r.x = o[i][0] * inv; r.y = o[i][1] * inv;
        r.z = o[i][2] * inv; r.w = o[i][3] * inv;
        int row = q0 + ty * 4 + i;
        *(float4*)(ctx + (size_t)row * DMODEL + h * DKH + tx * 4) = r;
    }
}

// ---------------------------------------------------------------------------
// LayerNorm over last dim (768). One block per row, 256 threads.
// ---------------------------------------------------------------------------
__global__ __launch_bounds__(256)
void ln_kernel(const float* __restrict__ in, const float* __restrict__ g,
               const float* __restrict__ bta, float* __restrict__ out)
{
    __shared__ float red[8];
    const int row = blockIdx.x;
    const int tid = threadIdx.x;
    const float* x = in + (size_t)row * DMODEL;

    float v0 = x[tid], v1 = x[tid + 256], v2 = x[tid + 512];
    float s = v0 + v1 + v2;
#pragma unroll
    for (int off = 32; off > 0; off >>= 1) s += __shfl_xor(s, off);
    int wave = tid >> 6, lane = tid & 63;
    if (lane == 0) red[wave] = s;
    __syncthreads();
    float mu = (red[0] + red[1] + red[2] + red[3]) * (1.0f / DMODEL);

    float d0 = v0 - mu, d1 = v1 - mu, d2 = v2 - mu;
    float s2 = d0 * d0 + d1 * d1 + d2 * d2;
#pragma unroll
    for (int off = 32; off > 0; off >>= 1) s2 += __shfl_xor(s2, off);
    if (lane == 0) red[4 + wave] = s2;
    __syncthreads();
    float var = (red[4] + red[5] + red[6] + red[7]) * (1.0f / DMODEL);
    float rstd = rsqrtf(var + 1e-5f);

    float* y = out + (size_t)row * DMODEL;
    y[tid]       = d0 * rstd * g[tid]       + bta[tid];
    y[tid + 256] = d1 * rstd * g[tid + 256] + bta[tid + 256];
    y[tid + 512] = d2 * rstd * g[tid + 512] + bta[tid + 512];
}

// ---------------------------------------------------------------------------
// Launch: QKV -> attention -> O-proj(+x) -> LN1 -> FFN1(relu) -> FFN2(+h) -> LN2
// Workspace (floats):
//   [0 .. 9437184)      Q,K,V head-major (3 x 3145728)   } reused by FF1
//   [9437184 .. 12582912)  ctx (token-major)             }
//   [12582912 .. 15728640) s1 = x + attn_out ; later t2 = h + ffn_out
//   [15728640 .. 18874368) h (LN1 output)
// Peak: 75.5 MB.
// ---------------------------------------------------------------------------
extern "C" void kernel_launch(void* const* d_in, const int* in_sizes, int n_in,
                              void* d_out, int out_size, void* d_ws, size_t ws_size,
                              hipStream_t stream)
{
    const float* x  = (const float*)d_in[0];
    const float* Wq = (const float*)d_in[1];  const float* bq = (const float*)d_in[2];
    const float* Wk = (const float*)d_in[3];  const float* bk = (const float*)d_in[4];
    const float* Wv = (const float*)d_in[5];  const float* bv = (const float*)d_in[6];
    const float* Wo = (const float*)d_in[7];  const float* bo = (const float*)d_in[8];
    const float* W1 = (const float*)d_in[9];  const float* b1 = (const float*)d_in[10];
    const float* W2 = (const float*)d_in[11]; const float* b2 = (const float*)d_in[12];
    const float* g1 = (const float*)d_in[13]; const float* be1 = (const float*)d_in[14];
    const float* g2 = (const float*)d_in[15]; const float* be2 = (const float*)d_in[16];

    float* ws  = (float*)d_ws;
    float* qkv = ws;
    float* ctx = ws + 9437184;
    float* s1  = ws + 12582912;
    float* hb  = ws + 15728640;
    float* ff1 = ws;               // reuse Q/K/V + ctx
    float* t2  = ws + 12582912;    // reuse s1
    float* out = (float*)d_out;

    gemm_qkv<<<dim3(18, 32), 256, 0, stream>>>(x, Wq, bq, Wk, bk, Wv, bv, qkv);
    attn_kernel<<<dim3(64, NHEADS), 256, 0, stream>>>(qkv, ctx);
    gemm_generic<0, 1><<<dim3(6, 32), 256, 0, stream>>>(ctx, Wo, bo, x, s1, TSEQ, DMODEL, DMODEL);
    ln_kernel<<<TSEQ, 256, 0, stream>>>(s1, g1, be1, hb);
    gemm_generic<1, 0><<<dim3(24, 32), 256, 0, stream>>>(hb, W1, b1, nullptr, ff1, TSEQ, DFF, DMODEL);
    gemm_generic<0, 1><<<dim3(6, 32), 256, 0, stream>>>(ff1, W2, b2, hb, t2, TSEQ, DMODEL, DFF);
    ln_kernel<<<TSEQ, 256, 0, stream>>>(t2, g2, be2, out);
}

// Round 2
// 680.619 us; speedup vs baseline: 2.9713x; 2.9713x over previous
//
#include <hip/hip_runtime.h>
#include <math.h>

#define TSEQ 4096
#define DMODEL 768
#define NHEADS 12
#define DKH 64
#define DFF 3072

typedef __attribute__((ext_vector_type(4))) float f32x4;
typedef __attribute__((ext_vector_type(8))) short s16x8;
typedef unsigned short u16;
typedef unsigned int u32;

__device__ __forceinline__ u16 f2bf(float x) {
    u32 u = __builtin_bit_cast(u32, x);
    u32 r = u + 0x7FFFu + ((u >> 16) & 1u);
    return (u16)(r >> 16);
}
__device__ __forceinline__ float bf2f(u16 h) {
    u32 u = ((u32)h) << 16;
    return __builtin_bit_cast(float, u);
}

__device__ __forceinline__ void gll16(const void* g, void* lds) {
    __builtin_amdgcn_global_load_lds(
        (const __attribute__((address_space(1))) u32*)g,
        (__attribute__((address_space(3))) u32*)lds, 16, 0, 0);
}

// ---------------------------------------------------------------------------
// x [4096][768] f32 -> x'' [4096][2304] bf16  (hi | hi | lo)
// ---------------------------------------------------------------------------
__global__ __launch_bounds__(256) void split_x_kernel(const float* __restrict__ in,
                                                      u16* __restrict__ out)
{
    int idx = blockIdx.x * 256 + threadIdx.x;
    for (int i = idx; i < 786432; i += 262144) {   // 4096*192 float4 chunks
        int row = i / 192;
        int c = (i - row * 192) << 2;
        float4 v = *(const float4*)(in + (size_t)row * DMODEL + c);
        u16 h0 = f2bf(v.x), h1 = f2bf(v.y), h2 = f2bf(v.z), h3 = f2bf(v.w);
        u16 l0 = f2bf(v.x - bf2f(h0)), l1 = f2bf(v.y - bf2f(h1));
        u16 l2 = f2bf(v.z - bf2f(h2)), l3 = f2bf(v.w - bf2f(h3));
        u16* o = out + (size_t)row * 2304 + c;
        ushort4 hv = make_ushort4(h0, h1, h2, h3);
        *(ushort4*)(o)        = hv;
        *(ushort4*)(o + 768)  = hv;
        *(ushort4*)(o + 1536) = make_ushort4(l0, l1, l2, l3);
    }
}

// ---------------------------------------------------------------------------
// W [K][N] f32 -> out[(nofs+n)][3K] bf16 rows = (Whi^T | Wlo^T | Whi^T)
// grid (N/32, K/32), 256 threads, 32x32 LDS transpose tile.
// ---------------------------------------------------------------------------
__global__ __launch_bounds__(256) void wsplit(const float* __restrict__ W,
                                              u16* __restrict__ out,
                                              int K, int N, int nofs)
{
    __shared__ float t[32 * 33];
    const int tid = threadIdx.x;
    const int kt = blockIdx.y << 5, nt = blockIdx.x << 5;
    const int r = tid >> 3, c4 = tid & 7;
    float4 v = *(const float4*)(W + (size_t)(kt + r) * N + nt + (c4 << 2));
    t[r * 33 + (c4 << 2) + 0] = v.x;
    t[r * 33 + (c4 << 2) + 1] = v.y;
    t[r * 33 + (c4 << 2) + 2] = v.z;
    t[r * 33 + (c4 << 2) + 3] = v.w;
    __syncthreads();
    const int P3 = 3 * K;
    float a0 = t[((c4 << 2) + 0) * 33 + r];
    float a1 = t[((c4 << 2) + 1) * 33 + r];
    float a2 = t[((c4 << 2) + 2) * 33 + r];
    float a3 = t[((c4 << 2) + 3) * 33 + r];
    u16 h0 = f2bf(a0), h1 = f2bf(a1), h2 = f2bf(a2), h3 = f2bf(a3);
    u16 l0 = f2bf(a0 - bf2f(h0)), l1 = f2bf(a1 - bf2f(h1));
    u16 l2 = f2bf(a2 - bf2f(h2)), l3 = f2bf(a3 - bf2f(h3));
    u16* o = out + (size_t)(nofs + nt + r) * P3 + kt + (c4 << 2);
    ushort4 hv = make_ushort4(h0, h1, h2, h3);
    *(ushort4*)(o)         = hv;                               // Bh
    *(ushort4*)(o + K)     = make_ushort4(l0, l1, l2, l3);     // Bl
    *(ushort4*)(o + 2 * K) = hv;                               // Bh
}

__global__ __launch_bounds__(256) void bias_cat_kernel(const float* bq, const float* bk,
                                                       const float* bv, float* o)
{
    int i = blockIdx.x * 256 + threadIdx.x;
    if (i < 768) o[i] = bq[i];
    else if (i < 1536) o[i] = bk[i - 768];
    else if (i < 2304) o[i] = bv[i - 1536];
}

// ---------------------------------------------------------------------------
// bf16 MFMA GEMM over split operands. A[M][KP], B^T[N][KP] bf16, KP = 3K.
// BK=32, 4 waves (2x2), per-wave frags FMxFN of 16x16.
// EPI 0: QKV (bias cat, Q scale, writes Q/K head-major bf16 + V^T bf16)
// EPI 1: f32 out = acc + bias + R
// EPI 2: relu(acc+bias) -> split store (hi|hi|lo) to Cs with pitch 3*SEG
// ---------------------------------------------------------------------------
template<int BM, int BN, int EPI>
__global__ __launch_bounds__(256) void gemm_bf3(
    const u16* __restrict__ A, const u16* __restrict__ B,
    const float* __restrict__ bias, const float* __restrict__ R,
    float* __restrict__ Cf, u16* __restrict__ Cs,
    u16* __restrict__ Qb, u16* __restrict__ Kb, u16* __restrict__ VTb,
    int N, int KP, int SEG)
{
    constexpr int FM = BM / 32, FN = BN / 32, NC = BN / 2, NCP = NC + 4;
    __shared__ u16 As[BM * 32];
    __shared__ u16 Bs[BN * 32];
    __shared__ float Ep[4 * 16 * NCP];

    const int tid = threadIdx.x;
    const int w = tid >> 6, lane = tid & 63;
    const int wr = w >> 1, wc = w & 1;
    const int m0 = blockIdx.y * BM, n0 = blockIdx.x * BN;
    const int li = lane & 15, g = lane >> 4;

    f32x4 acc[FM][FN];
#pragma unroll
    for (int mi = 0; mi < FM; ++mi)
#pragma unroll
        for (int ni = 0; ni < FN; ++ni) acc[mi][ni] = (f32x4){0.f, 0.f, 0.f, 0.f};

    const int srow = lane >> 2, sc = lane & 3;
    for (int k0 = 0; k0 < KP; k0 += 32) {
        __syncthreads();
#pragma unroll
        for (int i = 0; i < BM / 64; ++i) {
            int inst = w * (BM / 64) + i;
            const u16* gp = A + (size_t)(m0 + inst * 16 + srow) * KP + k0 + sc * 8;
            gll16(gp, &As[inst * 512]);
        }
#pragma unroll
        for (int i = 0; i < BN / 64; ++i) {
            int inst = w * (BN / 64) + i;
            const u16* gp = B + (size_t)(n0 + inst * 16 + srow) * KP + k0 + sc * 8;
            gll16(gp, &Bs[inst * 512]);
        }
        __syncthreads();
        s16x8 af[FM], bf[FN];
#pragma unroll
        for (int mi = 0; mi < FM; ++mi)
            af[mi] = *(const s16x8*)&As[(wr * (BM / 2) + mi * 16 + li) * 32 + g * 8];
#pragma unroll
        for (int ni = 0; ni < FN; ++ni)
            bf[ni] = *(const s16x8*)&Bs[(wc * (BN / 2) + ni * 16 + li) * 32 + g * 8];
#pragma unroll
        for (int mi = 0; mi < FM; ++mi)
#pragma unroll
            for (int ni = 0; ni < FN; ++ni)
                acc[mi][ni] = __builtin_amdgcn_mfma_f32_16x16x32_bf16(
                    af[mi], bf[ni], acc[mi][ni], 0, 0, 0);
    }
    __syncthreads();

    // Epilogue: per-wave private LDS slice, coalesced writes.
    float* ep = Ep + w * 16 * NCP;
    const int colbase = n0 + wc * NC;
    const int rr = lane >> 2, ch = lane & 3;

#pragma unroll
    for (int mi = 0; mi < FM; ++mi) {
#pragma unroll
        for (int ni = 0; ni < FN; ++ni)
#pragma unroll
            for (int r = 0; r < 4; ++r)
                ep[(g * 4 + r) * NCP + ni * 16 + li] = acc[mi][ni][r];
        asm volatile("s_waitcnt lgkmcnt(0)" ::: "memory");

        const int grow0 = m0 + wr * (BM / 2) + mi * 16;
        const int grow = grow0 + rr;

        if constexpr (EPI == 1) {
#pragma unroll
            for (int q = 0; q < NC / 16; ++q) {
                int col = ch * (NC / 4) + q * 4;
                f32x4 v = *(f32x4*)&ep[rr * NCP + col];
                int gn = colbase + col;
                float4 bb = *(const float4*)(bias + gn);
                float4 rv = *(const float4*)(R + (size_t)grow * N + gn);
                float4 ov;
                ov.x = v[0] + bb.x + rv.x; ov.y = v[1] + bb.y + rv.y;
                ov.z = v[2] + bb.z + rv.z; ov.w = v[3] + bb.w + rv.w;
                *(float4*)(Cf + (size_t)grow * N + gn) = ov;
            }
        } else if constexpr (EPI == 2) {
#pragma unroll
            for (int q = 0; q < NC / 16; ++q) {
                int col = ch * (NC / 4) + q * 4;
                f32x4 v = *(f32x4*)&ep[rr * NCP + col];
                int gn = colbase + col;
                float4 bb = *(const float4*)(bias + gn);
                float x0 = fmaxf(v[0] + bb.x, 0.f), x1 = fmaxf(v[1] + bb.y, 0.f);
                float x2 = fmaxf(v[2] + bb.z, 0.f), x3 = fmaxf(v[3] + bb.w, 0.f);
                u16 h0 = f2bf(x0), h1 = f2bf(x1), h2 = f2bf(x2), h3 = f2bf(x3);
                u16 l0 = f2bf(x0 - bf2f(h0)), l1 = f2bf(x1 - bf2f(h1));
                u16 l2 = f2bf(x2 - bf2f(h2)), l3 = f2bf(x3 - bf2f(h3));
                u16* o = Cs + (size_t)grow * (3 * SEG) + gn;
                ushort4 hv = make_ushort4(h0, h1, h2, h3);
                *(ushort4*)(o)           = hv;
                *(ushort4*)(o + SEG)     = hv;
                *(ushort4*)(o + 2 * SEG) = make_ushort4(l0, l1, l2, l3);
            }
        } else {  // EPI 0: QKV
            const int seg = colbase / 768;           // wave-uniform
            const int hh = (colbase % 768) >> 6;     // wave-uniform head
            if (seg < 2) {
                u16* dst = (seg == 0) ? Qb : Kb;
                const float sc2 = (seg == 0) ? 0.125f : 1.0f;
#pragma unroll
                for (int q = 0; q < NC / 16; ++q) {
                    int col = ch * (NC / 4) + q * 4;
                    f32x4 v = *(f32x4*)&ep[rr * NCP + col];
                    float4 bb = *(const float4*)(bias + colbase + col);
                    u16 h0 = f2bf((v[0] + bb.x) * sc2);
                    u16 h1 = f2bf((v[1] + bb.y) * sc2);
                    u16 h2 = f2bf((v[2] + bb.z) * sc2);
                    u16 h3 = f2bf((v[3] + bb.w) * sc2);
                    *(ushort4*)&dst[((size_t)(hh << 12) + grow) * 64 + col] =
                        make_ushort4(h0, h1, h2, h3);
                }
            } else {
                // V: transposed readout, lane <-> column (d), write V^T[h][d][tok]
                float bb = bias[colbase + lane];
                s16x8 pa, pb;
#pragma unroll
                for (int r2 = 0; r2 < 8; ++r2)
                    pa[r2] = (short)f2bf(ep[r2 * NCP + lane] + bb);
#pragma unroll
                for (int r2 = 0; r2 < 8; ++r2)
                    pb[r2] = (short)f2bf(ep[(8 + r2) * NCP + lane] + bb);
                u16* ov = VTb + ((size_t)(hh << 6) + lane) * TSEQ + grow0;
                *(s16x8*)(ov)     = pa;
                *(s16x8*)(ov + 8) = pb;
            }
        }
    }
}

// ---------------------------------------------------------------------------
// Flash attention, bf16 MFMA, causal. Block = 64 q-rows x 1 head, 4 waves.
// Q prescaled by 0.125. K,V^T staged in XOR-swizzled LDS. P per-wave in LDS.
// Output: ctx'' [4096][2304] bf16 split format (hi|hi|lo).
// ---------------------------------------------------------------------------
__global__ __launch_bounds__(256) void attn_mfma(
    const u16* __restrict__ Qb, const u16* __restrict__ Kb,
    const u16* __restrict__ VTb, u16* __restrict__ ctxs)
{
    __shared__ u16 Ks[64 * 64];
    __shared__ u16 Vs[64 * 64];
    __shared__ u16 Ps[4][16 * 64];

    const int tid = threadIdx.x, w = tid >> 6, lane = tid & 63;
    const int qb = 63 - (int)blockIdx.x;      // heavy blocks first
    const int h = blockIdx.y;
    const int q0 = qb << 6;
    const int g = lane >> 4, li = lane & 15, l7 = lane & 7;

    s16x8 qf[2];
    {
        const u16* qrow = Qb + ((size_t)(h << 12) + q0 + (w << 4) + li) * 64 + g * 8;
        qf[0] = *(const s16x8*)(qrow);
        qf[1] = *(const s16x8*)(qrow + 32);
    }

    f32x4 o[4];
    float m_[4], l_[4];
#pragma unroll
    for (int i = 0; i < 4; ++i) {
        o[i] = (f32x4){0.f, 0.f, 0.f, 0.f};
        m_[i] = -1e30f; l_[i] = 0.f;
    }

    const int srow = tid >> 3, sch = tid & 7;
    for (int kb = 0; kb <= qb; ++kb) {
        __syncthreads();
#pragma unroll
        for (int it = 0; it < 2; ++it) {
            int row = srow + it * 32;
            s16x8 kv = *(const s16x8*)(Kb + ((size_t)(h << 12) + (kb << 6) + row) * 64 + sch * 8);
            s16x8 vv = *(const s16x8*)(VTb + ((size_t)(h << 6) + row) * TSEQ + (kb << 6) + sch * 8);
            int sw = (sch * 8) ^ ((row & 7) << 3);
            *(s16x8*)&Ks[row * 64 + sw] = kv;
            *(s16x8*)&Vs[row * 64 + sw] = vv;
        }
        __syncthreads();

        f32x4 s[4];
#pragma unroll
        for (int n = 0; n < 4; ++n) s[n] = (f32x4){0.f, 0.f, 0.f, 0.f};
#pragma unroll
        for (int ks = 0; ks < 2; ++ks) {
            int koff = (ks * 32 + g * 8) ^ (l7 << 3);
#pragma unroll
            for (int n = 0; n < 4; ++n) {
                s16x8 kf = *(const s16x8*)&Ks[(n * 16 + li) * 64 + koff];
                s[n] = __builtin_amdgcn_mfma_f32_16x16x32_bf16(qf[ks], kf, s[n], 0, 0, 0);
            }
        }

        if (kb == qb) {
#pragma unroll
            for (int n = 0; n < 4; ++n)
#pragma unroll
                for (int r = 0; r < 4; ++r) {
                    int qrow = (w << 4) + g * 4 + r;
                    int kcol = n * 16 + li;
                    if (kcol > qrow) s[n][r] = -1e30f;
                }
        }

#pragma unroll
        for (int r = 0; r < 4; ++r) {
            float rm = fmaxf(fmaxf(s[0][r], s[1][r]), fmaxf(s[2][r], s[3][r]));
            rm = fmaxf(rm, __shfl_xor(rm, 1, 16));
            rm = fmaxf(rm, __shfl_xor(rm, 2, 16));
            rm = fmaxf(rm, __shfl_xor(rm, 4, 16));
            rm = fmaxf(rm, __shfl_xor(rm, 8, 16));
            float mn = fmaxf(m_[r], rm);
            float scl = __expf(m_[r] - mn);
            m_[r] = mn;
            float rs = 0.f;
            int prow = g * 4 + r;
            int psw = (prow & 7) << 3;
#pragma unroll
            for (int n = 0; n < 4; ++n) {
                float e = __expf(s[n][r] - mn);
                rs += e;
                Ps[w][prow * 64 + ((n * 16 + li) ^ psw)] = f2bf(e);
            }
            rs += __shfl_xor(rs, 1, 16);
            rs += __shfl_xor(rs, 2, 16);
            rs += __shfl_xor(rs, 4, 16);
            rs += __shfl_xor(rs, 8, 16);
            l_[r] = l_[r] * scl + rs;
#pragma unroll
            for (int d16 = 0; d16 < 4; ++d16) o[d16][r] *= scl;
        }
        asm volatile("s_waitcnt lgkmcnt(0)" ::: "memory");

#pragma unroll
        for (int ks = 0; ks < 2; ++ks) {
            int koff = (ks * 32 + g * 8) ^ (l7 << 3);
            s16x8 pf = *(const s16x8*)&Ps[w][li * 64 + koff];
#pragma unroll
            for (int d16 = 0; d16 < 4; ++d16) {
                s16x8 vf = *(const s16x8*)&Vs[(d16 * 16 + li) * 64 + koff];
                o[d16] = __builtin_amdgcn_mfma_f32_16x16x32_bf16(pf, vf, o[d16], 0, 0, 0);
            }
        }
    }

#pragma unroll
    for (int r = 0; r < 4; ++r) {
        float inv = 1.0f / l_[r];
        int grow = q0 + (w << 4) + g * 4 + r;
#pragma unroll
        for (int d16 = 0; d16 < 4; ++d16) {
            float v = o[d16][r] * inv;
            u16 hi = f2bf(v);
            u16 lo = f2bf(v - bf2f(hi));
            int col = (h << 6) + d16 * 16 + li;
            u16* o2 = ctxs + (size_t)grow * 2304 + col;
            o2[0] = hi; o2[768] = hi; o2[1536] = lo;
        }
    }
}

// ---------------------------------------------------------------------------
// LayerNorm over 768. SPLIT=1 also emits bf16 split (hi|hi|lo) operand.
// ---------------------------------------------------------------------------
template<int SPLIT>
__global__ __launch_bounds__(256) void ln_kernel(const float* __restrict__ in,
    const float* __restrict__ gw, const float* __restrict__ bw,
    float* __restrict__ outf, u16* __restrict__ outs)
{
    __shared__ float red[8];
    const int row = blockIdx.x, tid = threadIdx.x;
    const float* x = in + (size_t)row * DMODEL;
    float v0 = x[tid], v1 = x[tid + 256], v2 = x[tid + 512];
    float s = v0 + v1 + v2;
#pragma unroll
    for (int off = 32; off > 0; off >>= 1) s += __shfl_xor(s, off, 64);
    const int wv = tid >> 6, lane = tid & 63;
    if (lane == 0) red[wv] = s;
    __syncthreads();
    float mu = (red[0] + red[1] + red[2] + red[3]) * (1.0f / DMODEL);
    float d0 = v0 - mu, d1 = v1 - mu, d2 = v2 - mu;
    float s2 = d0 * d0 + d1 * d1 + d2 * d2;
#pragma unroll
    for (int off = 32; off > 0; off >>= 1) s2 += __shfl_xor(s2, off, 64);
    if (lane == 0) red[4 + wv] = s2;
    __syncthreads();
    float var = (red[4] + red[5] + red[6] + red[7]) * (1.0f / DMODEL);
    float rstd = rsqrtf(var + 1e-5f);
    float y0 = d0 * rstd * gw[tid] + bw[tid];
    float y1 = d1 * rstd * gw[tid + 256] + bw[tid + 256];
    float y2 = d2 * rstd * gw[tid + 512] + bw[tid + 512];
    float* yo = outf + (size_t)row * DMODEL;
    yo[tid] = y0; yo[tid + 256] = y1; yo[tid + 512] = y2;
    if constexpr (SPLIT) {
        u16* o = outs + (size_t)row * 2304;
        u16 h0 = f2bf(y0), h1 = f2bf(y1), h2 = f2bf(y2);
        o[tid] = h0;       o[768 + tid] = h0;       o[1536 + tid] = f2bf(y0 - bf2f(h0));
        o[tid + 256] = h1; o[1024 + tid] = h1;      o[1792 + tid] = f2bf(y1 - bf2f(h1));
        o[tid + 512] = h2; o[1280 + tid] = h2;      o[2048 + tid] = f2bf(y2 - bf2f(h2));
    }
}

// ---------------------------------------------------------------------------
// Workspace layout (bytes):
//  [0, 75.5M)  region reused by ff1'' later:
//    xs@0 (18.9M) | Qb@18874368 | Kb@25165824 | VTb@31457280 | ctxs@37748736
//    Wqkvs@56623104 | Wos@67239936 | bcat@70778880 | s1@70788096 (ends 83.4M)
//  W1s@83371008 | W2s@97526784 | h@111682560 | hs@124265472 | t2@143139840
//  total ~155.7 MB
// ---------------------------------------------------------------------------
extern "C" void kernel_launch(void* const* d_in, const int* in_sizes, int n_in,
                              void* d_out, int out_size, void* d_ws, size_t ws_size,
                              hipStream_t stream)
{
    const float* x  = (const float*)d_in[0];
    const float* Wq = (const float*)d_in[1];  const float* bq = (const float*)d_in[2];
    const float* Wk = (const float*)d_in[3];  const float* bk = (const float*)d_in[4];
    const float* Wv = (const float*)d_in[5];  const float* bv = (const float*)d_in[6];
    const float* Wo = (const float*)d_in[7];  const float* bo = (const float*)d_in[8];
    const float* W1 = (const float*)d_in[9];  const float* b1 = (const float*)d_in[10];
    const float* W2 = (const float*)d_in[11]; const float* b2 = (const float*)d_in[12];
    const float* g1 = (const float*)d_in[13]; const float* be1 = (const float*)d_in[14];
    const float* g2 = (const float*)d_in[15]; const float* be2 = (const float*)d_in[16];
    float* out = (float*)d_out;

    char* wsb = (char*)d_ws;
    u16*   xs    = (u16*)(wsb + 0);
    u16*   Qb    = (u16*)(wsb + 18874368);
    u16*   Kb2   = (u16*)(wsb + 25165824);
    u16*   VTb   = (u16*)(wsb + 31457280);
    u16*   ctxs  = (u16*)(wsb + 37748736);
    u16*   Wqkvs = (u16*)(wsb + 56623104);
    u16*   Wos   = (u16*)(wsb + 67239936);
    float* bcat  = (float*)(wsb + 70778880);
    float* s1    = (float*)(wsb + 70788096);
    u16*   ff1s  = (u16*)(wsb + 0);
    u16*   W1s   = (u16*)(wsb + 83371008);
    u16*   W2s   = (u16*)(wsb + 97526784);
    float* h     = (float*)(wsb + 111682560);
    u16*   hs    = (u16*)(wsb + 124265472);
    float* t2    = (float*)(wsb + 143139840);

    split_x_kernel<<<1024, 256, 0, stream>>>(x, xs);
    wsplit<<<dim3(24, 24), 256, 0, stream>>>(Wq, Wqkvs, 768, 768, 0);
    wsplit<<<dim3(24, 24), 256, 0, stream>>>(Wk, Wqkvs, 768, 768, 768);
    wsplit<<<dim3(24, 24), 256, 0, stream>>>(Wv, Wqkvs, 768, 768, 1536);
    wsplit<<<dim3(24, 24), 256, 0, stream>>>(Wo, Wos, 768, 768, 0);
    wsplit<<<dim3(96, 24), 256, 0, stream>>>(W1, W1s, 768, 3072, 0);
    wsplit<<<dim3(24, 96), 256, 0, stream>>>(W2, W2s, 3072, 768, 0);
    bias_cat_kernel<<<9, 256, 0, stream>>>(bq, bk, bv, bcat);

    gemm_bf3<128, 128, 0><<<dim3(18, 32), 256, 0, stream>>>(
        xs, Wqkvs, bcat, nullptr, nullptr, nullptr, Qb, Kb2, VTb, 2304, 2304, 0);
    attn_mfma<<<dim3(64, 12), 256, 0, stream>>>(Qb, Kb2, VTb, ctxs);
    gemm_bf3<64, 64, 1><<<dim3(12, 64), 256, 0, stream>>>(
        ctxs, Wos, bo, x, s1, nullptr, nullptr, nullptr, nullptr, 768, 2304, 0);
    ln_kernel<1><<<4096, 256, 0, stream>>>(s1, g1, be1, h, hs);
    gemm_bf3<128, 128, 2><<<dim3(24, 32), 256, 0, stream>>>(
        hs, W1s, b1, nullptr, nullptr, ff1s, nullptr, nullptr, nullptr, 3072, 2304, 3072);
    gemm_bf3<64, 64, 1><<<dim3(12, 64), 256, 0, stream>>>(
        ff1s, W2s, b2, h, t2, nullptr, nullptr, nullptr, nullptr, 768, 9216, 0);
    ln_kernel<0><<<4096, 256, 0, stream>>>(t2, g2, be2, out, nullptr);
}